// Round 7
// baseline (139.544 us; speedup 1.0000x reference)
//
#include <hip/hip_runtime.h>

// Problem constants (B=2, S=2048, H=8, E=64).
// Harness passes f16 tensors upcast to FLOAT32 (in and out). Internally f16
// compute (lossless re-narrowing of f16-origin data), fp32 MFMA accumulation.
#define S_LEN 2048
#define NH    8
#define EMB   64
#define BM    64    // q rows per block (16 per wave)
#define BN    64    // kv tile length
#define NKT   (S_LEN / BN)          // 32 kv tiles
#define NSPLIT 3    // 16 bh x 32 qt x 3 = 1536 blocks = 2 rounds x 3/CU exactly
#define M_INIT  (-1.0e4f)
#define EXP_CLAMP (-80.0f)
#define DEFER_THR 8.0f   // T13: skip rescale while max growth <= 8 (P <= e^8, f16-safe)

typedef _Float16 half8   __attribute__((ext_vector_type(8)));
typedef _Float16 half4   __attribute__((ext_vector_type(4)));
typedef float    float4_t __attribute__((ext_vector_type(4)));
typedef float    float8_t __attribute__((ext_vector_type(8)));

__device__ inline half8 cvt8(const float* p) {
    float8_t f = *reinterpret_cast<const float8_t*>(p);
    half8 h;
    #pragma unroll
    for (int j = 0; j < 8; ++j) h[j] = (_Float16)f[j];
    return h;
}

// async global->LDS, 16B per lane; LDS dest = uniform base + lane*16
__device__ inline void gload_lds16(const _Float16* g, _Float16* l) {
    __builtin_amdgcn_global_load_lds(
        (const __attribute__((address_space(1))) void*)g,
        (__attribute__((address_space(3))) void*)l, 16, 0, 0);
}

// ---------------------------------------------------------------------------
// Projection worker: one segment per 256 blocks.
//   mode 0: Q -> Qf16[bh][s][e], f16, pre-scaled by 0.125
//   mode 1: K -> KT8[bh][f/8][s][f%8]
//   mode 2: V -> VT8[bh][s/8][f][s%8]
// ---------------------------------------------------------------------------
__device__ inline void proj_body(
    int mode, int bid, const float* __restrict__ X,
    const float* __restrict__ W, const float* __restrict__ bias,
    _Float16* __restrict__ Dst)
{
    const int tid  = threadIdx.x;
    const int lane = tid & 63;
    const int wave = tid >> 6;
    const int l15  = lane & 15;
    const int quad = lane >> 4;
    const int gwave = bid * 4 + wave;

    half8 wf[4][2];
    #pragma unroll
    for (int ft = 0; ft < 4; ++ft)
        #pragma unroll
        for (int ks = 0; ks < 2; ++ks)
            wf[ft][ks] = cvt8(W + (ft * 16 + l15) * 64 + ks * 32 + quad * 8);
    float bv[4];
    #pragma unroll
    for (int ft = 0; ft < 4; ++ft) bv[ft] = bias[ft * 16 + l15];

    #pragma unroll
    for (int rt2 = 0; rt2 < 2; ++rt2) {
        const int rt = gwave * 2 + rt2;
        const int arow = rt * 16 + l15;
        half8 xf[2];
        #pragma unroll
        for (int ks = 0; ks < 2; ++ks)
            xf[ks] = cvt8(X + (long)arow * 64 + ks * 32 + quad * 8);
        float4_t acc[4];
        #pragma unroll
        for (int ft = 0; ft < 4; ++ft) {
            acc[ft] = (float4_t){0.f, 0.f, 0.f, 0.f};
            #pragma unroll
            for (int ks = 0; ks < 2; ++ks)
                acc[ft] = __builtin_amdgcn_mfma_f32_16x16x32_f16(
                    xf[ks], wf[ft][ks], acc[ft], 0, 0, 0);
        }
        #pragma unroll
        for (int r = 0; r < 4; ++r) {
            const int row = rt * 16 + quad * 4 + r;     // (b*S+s)*H+h
            const int b = row >> 14;
            const int s = (row >> 3) & 2047;
            const int h = row & 7;
            const int bh = b * NH + h;
            #pragma unroll
            for (int ft = 0; ft < 4; ++ft) {
                const _Float16 v = (_Float16)(acc[ft][r] + bv[ft]);
                const int f = ft * 16 + l15;
                if (mode == 0)
                    Dst[((long)bh * S_LEN + s) * EMB + f] = v * (_Float16)0.125f;
                else if (mode == 1)
                    Dst[(((long)bh * 8 + (f >> 3)) * S_LEN + s) * 8 + (f & 7)] = v;
                else
                    Dst[(((long)bh * 256 + (s >> 3)) * 64 + f) * 8 + (s & 7)] = v;
            }
        }
    }
}

// Launch 1 (512 blocks): seg 0 = Q -> Qf16 (d_out[0,4MiB)), seg 1 = K -> KT8
// (d_out[4MiB,8MiB)). Both are EXACTLY 4,194,304 B; d_out is 8,388,608 B.
__global__ __launch_bounds__(256) void proj_qk(
    const float* __restrict__ q_in, const float* __restrict__ k_in,
    const float* __restrict__ Wq, const float* __restrict__ bq,
    const float* __restrict__ Wk, const float* __restrict__ bk,
    _Float16* __restrict__ Qf16, _Float16* __restrict__ KT8)
{
    const int seg = blockIdx.x >> 8;
    const int bid = blockIdx.x & 255;
    if (seg == 0) proj_body(0, bid, q_in, Wq, bq, Qf16);
    else          proj_body(1, bid, k_in, Wk, bk, KT8);
}

// Launch 2 (256 blocks): V -> VT8 (in d_in[1]; k_in dead after launch 1).
__global__ __launch_bounds__(256) void proj_v(
    const float* __restrict__ v_in,
    const float* __restrict__ Wv, const float* __restrict__ bv_,
    _Float16* __restrict__ VT8)
{
    proj_body(2, blockIdx.x, v_in, Wv, bv_, VT8);
}

// ---------------------------------------------------------------------------
// Launch 3: flash attention partials. KV-split=3, S^T orientation, BN=64.
// R7 restructure: SKEWED PIPELINE (T15) — QK(i+1) issues on the MFMA pipe
// while softmax(i) runs on the VALU pipe; the QK latency + max tree leave the
// per-tile critical chain. Buffering: K double (K(i) dead after QK(i) one
// iteration early), V TRIPLE (V(i) reading / V(i+1) ready / V(i+2) staging).
// LDS = 16K K + 24K V + 8K P = 48 KB -> 3 blocks/CU; grid 1536 = 2 clean
// rounds of 768. Hazards: every LDS-buffer reuse pair is separated by a
// barrier (incl. the one-time barrier after QK(0) protecting Kb[0] from
// iter-0's stage of tile 2).
// Kept (verified R3/R6): f16 Q direct loads, ones-MFMA l, max3 tree, T13
// defer-max zero-crosslane common path, T5 setprio, XCD swizzle, P XOR-swz.
// ---------------------------------------------------------------------------
__global__ __launch_bounds__(256, 3) void attn_part(
    const _Float16* __restrict__ KT, const _Float16* __restrict__ VT,
    const _Float16* __restrict__ Qf16,
    _Float16* __restrict__ p0, _Float16* __restrict__ p1,
    _Float16* __restrict__ p2, float* __restrict__ stats)
{
    __shared__ __align__(16) _Float16 Kb[2][8 * 64 * 8];   // 2 x 8 KB [ec][tl][ej]
    __shared__ __align__(16) _Float16 Vb[3][8 * 64 * 8];   // 3 x 8 KB [tc][e][tj]
    __shared__ __align__(16) _Float16 Pl[4][16 * 64];      // 8 KB per-wave P (swizzled)

    const int tid  = threadIdx.x;
    const int lane = tid & 63;
    const int wave = tid >> 6;
    const int l15  = lane & 15;
    const int quad = lane >> 4;

    // XCD-aware decomposition: 1536 = 8 XCD * (2 heads * 96 blocks)
    const int bx     = blockIdx.x;
    const int xcd    = bx & 7;
    const int j      = bx >> 3;             // 0..191 within this XCD
    const int hh     = (j >= 96) ? 1 : 0;   // which of the 2 heads here
    const int within = j - hh * 96;         // 0..95 = qt*NSPLIT + sp
    const int bh     = xcd * 2 + hh;
    const int qt     = within / NSPLIT;
    const int sp     = within - qt * NSPLIT;

    const int qrow0 = qt * BM + wave * 16;
    const _Float16* kg  = KT + (long)bh * 8 * S_LEN * 8;  // head base in KT8
    const _Float16* vgh = VT + (long)bh * 256 * 512;      // head base in VT8

    // per-thread staging bases (constant per-tile offsets added in loop)
    const _Float16* k0 = kg + ((long)(tid >> 6) * S_LEN + (tid & 63)) * 8;
    const _Float16* k1 = kg + ((long)((tid >> 6) + 4) * S_LEN + (tid & 63)) * 8;
    const _Float16* v0 = vgh + tid * 8;
    const _Float16* v1 = vgh + (256 + tid) * 8;

    const int kb = (sp * NKT) / NSPLIT, ke = ((sp + 1) * NKT) / NSPLIT;
    const int ntile = ke - kb;                             // 10/11/11

    // ---- prologue: stage tiles kb, kb+1; load Q frags meanwhile ----
    {
        const long t8  = (long)(kb * BN) * 8;
        const long t64 = (long)(kb * BN) * 64;
        gload_lds16(k0 + t8,  &Kb[0][tid * 8]);
        gload_lds16(k1 + t8,  &Kb[0][(256 + tid) * 8]);
        gload_lds16(v0 + t64, &Vb[0][tid * 8]);
        gload_lds16(v1 + t64, &Vb[0][(256 + tid) * 8]);
    }
    {
        const long t8  = (long)((kb + 1) * BN) * 8;
        const long t64 = (long)((kb + 1) * BN) * 64;
        gload_lds16(k0 + t8,  &Kb[1][tid * 8]);
        gload_lds16(k1 + t8,  &Kb[1][(256 + tid) * 8]);
        gload_lds16(v0 + t64, &Vb[1][tid * 8]);
        gload_lds16(v1 + t64, &Vb[1][(256 + tid) * 8]);
    }

    half8 qf[2];   // B-frag: Q[n = q-row l15][e = ks*32+quad*8+j] (f16 direct)
    {
        const _Float16* qrow = Qf16 + ((long)bh * S_LEN + qrow0 + l15) * EMB;
        qf[0] = *reinterpret_cast<const half8*>(qrow + quad * 8);
        qf[1] = *reinterpret_cast<const half8*>(qrow + 32 + quad * 8);
    }

    half8 vones;   // B-frag of all-ones for the l row-sum MFMA
    #pragma unroll
    for (int jj = 0; jj < 8; ++jj) vones[jj] = (_Float16)1.0f;

    float4_t o[4];
    #pragma unroll
    for (int et = 0; et < 4; ++et) o[et] = (float4_t){0.f, 0.f, 0.f, 0.f};
    float4_t lacc = (float4_t){0.f, 0.f, 0.f, 0.f};  // P row-sums, rows quad*4+r
    float m_run = M_INIT;      // running (possibly stale) max for q-row l15

    const int pswz = (l15 & 7) << 3;      // P column XOR-swizzle
    _Float16* Pw = Pl[wave];

    __syncthreads();                      // drains prologue stages (both tiles)

    // ---- QK(0) into cur ----
    float4_t cur[4];
    #pragma unroll
    for (int nt = 0; nt < 4; ++nt) cur[nt] = (float4_t){0.f, 0.f, 0.f, 0.f};
    __builtin_amdgcn_s_setprio(1);
    #pragma unroll
    for (int nt = 0; nt < 4; ++nt)
        #pragma unroll
        for (int ks = 0; ks < 2; ++ks) {
            half8 kf = *reinterpret_cast<const half8*>(
                &Kb[0][(ks * 4 + quad) * 512 + (nt * 16 + l15) * 8]);
            cur[nt] = __builtin_amdgcn_mfma_f32_16x16x32_f16(
                kf, qf[ks], cur[nt], 0, 0, 0);
        }
    __builtin_amdgcn_s_setprio(0);
    __syncthreads();    // all waves done reading Kb[0] before iter-0 stages it

    int vs_stage = 2;   // Vb slot receiving tile it+2
    int vs_pv    = 0;   // Vb slot holding tile it

    for (int it = 0; it < ntile; ++it) {
        // ---- 1. stage tile it+2 -> Kb[it&1] (K(it) dead), Vb[vs_stage] ----
        if (it + 2 < ntile) {
            const long t8  = (long)((kb + it + 2) * BN) * 8;
            const long t64 = (long)((kb + it + 2) * BN) * 64;
            _Float16* kd = Kb[it & 1];
            _Float16* vd = Vb[vs_stage];
            gload_lds16(k0 + t8,  kd + tid * 8);
            gload_lds16(k1 + t8,  kd + (256 + tid) * 8);
            gload_lds16(v0 + t64, vd + tid * 8);
            gload_lds16(v1 + t64, vd + (256 + tid) * 8);
        }

        // ---- 2. QK(it+1) on the MFMA pipe (independent of softmax(it)) ----
        float4_t nxt[4];
        #pragma unroll
        for (int nt = 0; nt < 4; ++nt) nxt[nt] = (float4_t){0.f, 0.f, 0.f, 0.f};
        if (it + 1 < ntile) {
            const _Float16* Kc = Kb[(it + 1) & 1];
            __builtin_amdgcn_s_setprio(1);
            #pragma unroll
            for (int nt = 0; nt < 4; ++nt)
                #pragma unroll
                for (int ks = 0; ks < 2; ++ks) {
                    half8 kf = *reinterpret_cast<const half8*>(
                        Kc + (ks * 4 + quad) * 512 + (nt * 16 + l15) * 8);
                    nxt[nt] = __builtin_amdgcn_mfma_f32_16x16x32_f16(
                        kf, qf[ks], nxt[nt], 0, 0, 0);
                }
            __builtin_amdgcn_s_setprio(0);
        }

        // ---- 3. softmax(it) on cur (VALU; overlaps step 2) ----
        float mx = fmaxf(fmaxf(cur[0][0], cur[0][1]),
                         fmaxf(cur[0][2], cur[0][3]));
        mx = fmaxf(fmaxf(mx, cur[1][0]), cur[1][1]);
        mx = fmaxf(fmaxf(mx, cur[1][2]), cur[1][3]);
        mx = fmaxf(fmaxf(mx, cur[2][0]), cur[2][1]);
        mx = fmaxf(fmaxf(mx, cur[2][2]), cur[2][3]);
        mx = fmaxf(fmaxf(mx, cur[3][0]), cur[3][1]);
        mx = fmaxf(fmaxf(mx, cur[3][2]), cur[3][3]);

        // T13 defer: wave-wide vote covers every row's every value.
        if (!__all(mx - m_run <= DEFER_THR)) {
            float mr = fmaxf(mx, __shfl_xor(mx, 16));
            mr = fmaxf(mr, __shfl_xor(mr, 32));
            const float mn = fmaxf(m_run, mr);
            const float alpha = __expf(fmaxf(m_run - mn, EXP_CLAMP));
            m_run = mn;
            #pragma unroll
            for (int r = 0; r < 4; ++r) {  // o/lacc rows are quad*4+r
                const float ar = __shfl(alpha, quad * 4 + r);
                lacc[r] *= ar;
                #pragma unroll
                for (int et = 0; et < 4; ++et) o[et][r] *= ar;
            }
        }

        // ---- 4. exp + P store by nt-pairs; PV(ts) + l-MFMA interleaved ----
        const _Float16* Vc = Vb[vs_pv];
        #pragma unroll
        for (int ts = 0; ts < 2; ++ts) {
            #pragma unroll
            for (int ntl = 0; ntl < 2; ++ntl) {
                const int nt = ts * 2 + ntl;
                half4 ph;
                #pragma unroll
                for (int r = 0; r < 4; ++r)
                    ph[r] = (_Float16)__expf(cur[nt][r] - m_run);
                *reinterpret_cast<half4*>(
                    &Pw[l15 * 64 + ((nt * 16 + quad * 4) ^ pswz)]) = ph;
            }
            // A-frag = P[m=l15][t = ts*32 + quad*8 + j] (intra-wave LDS RAW)
            half8 pf = *reinterpret_cast<const half8*>(
                &Pw[l15 * 64 + ((ts * 32 + quad * 8) ^ pswz)]);
            __builtin_amdgcn_s_setprio(1);
            #pragma unroll
            for (int et = 0; et < 4; ++et) {
                half8 vf = *reinterpret_cast<const half8*>(
                    Vc + (ts * 4 + quad) * 512 + (et * 16 + l15) * 8);
                o[et] = __builtin_amdgcn_mfma_f32_16x16x32_f16(pf, vf, o[et], 0, 0, 0);
            }
            lacc = __builtin_amdgcn_mfma_f32_16x16x32_f16(pf, vones, lacc, 0, 0, 0);
            __builtin_amdgcn_s_setprio(0);
        }

        // ---- 5. barrier: drains stage(it+2) (a full phase old by next use);
        //         separates all buffer reuse across waves ----
        if (it + 1 < ntile) __syncthreads();

        #pragma unroll
        for (int nt = 0; nt < 4; ++nt) cur[nt] = nxt[nt];
        vs_pv    = (vs_pv == 2)    ? 0 : vs_pv + 1;
        vs_stage = (vs_stage == 2) ? 0 : vs_stage + 1;
    }

    // ---- epilogue: lacc[r] IS the row sum for row quad*4+r (no shuffles) ----
    _Float16* pp = (sp == 0) ? p0 : (sp == 1) ? p1 : p2;
    #pragma unroll
    for (int r = 0; r < 4; ++r) {
        const float inv = 1.f / lacc[r];
        const int row = qrow0 + quad * 4 + r;            // 0..2047 within head
        const int R = bh * S_LEN + row;                  // 0..32767 global row
        #pragma unroll
        for (int et = 0; et < 4; ++et)
            pp[(long)R * EMB + et * 16 + l15] = (_Float16)(o[et][r] * inv);
    }
    // stats: lane i (<16) owns q-row i. l for row=lane lives at quad lane>>2,
    // component lane&3 (uniform across l15) -> 4 shuffles + select.
    {
        const int srcl = (lane >> 2) * 16;
        const float s0 = __shfl(lacc[0], srcl);
        const float s1 = __shfl(lacc[1], srcl);
        const float s2 = __shfl(lacc[2], srcl);
        const float s3 = __shfl(lacc[3], srcl);
        const int rr = lane & 3;
        const float lsel = (rr == 0) ? s0 : (rr == 1) ? s1 : (rr == 2) ? s2 : s3;
        if (lane < 16) {
            const int R = bh * S_LEN + qrow0 + lane;
            stats[sp * 32768 + R] = m_run;
            stats[(NSPLIT + sp) * 32768 + R] = lsel;
        }
    }
}

// ---------------------------------------------------------------------------
// Launch 4: combine the 3 partials. O = sum w_i*Ohat_i, f16-round, f32 store.
// Stale-m partials are exact here: w_i = l_i * exp(m_i - M) is invariant.
// ---------------------------------------------------------------------------
__global__ __launch_bounds__(256) void attn_combine(
    const _Float16* __restrict__ p0, const _Float16* __restrict__ p1,
    const _Float16* __restrict__ p2, const float* __restrict__ stats,
    float* __restrict__ out)
{
    const int gid = blockIdx.x * 256 + threadIdx.x;      // 131072 threads
    const int R  = gid >> 2;
    const int c0 = (gid & 3) * 16;
    const float m0 = stats[R], m1 = stats[32768 + R], m2 = stats[2 * 32768 + R];
    const float l0 = stats[3 * 32768 + R], l1 = stats[4 * 32768 + R],
                l2 = stats[5 * 32768 + R];
    const float M = fmaxf(fmaxf(m0, m1), m2);
    float w0 = l0 * __expf(fmaxf(m0 - M, EXP_CLAMP));
    float w1 = l1 * __expf(fmaxf(m1 - M, EXP_CLAMP));
    float w2 = l2 * __expf(fmaxf(m2 - M, EXP_CLAMP));
    const float rinv = 1.f / (w0 + w1 + w2);
    w0 *= rinv; w1 *= rinv; w2 *= rinv;
    const long i0 = (long)R * EMB + c0;
    #pragma unroll
    for (int h = 0; h < 2; ++h) {
        half8 a = *reinterpret_cast<const half8*>(p0 + i0 + h * 8);
        half8 b = *reinterpret_cast<const half8*>(p1 + i0 + h * 8);
        half8 c = *reinterpret_cast<const half8*>(p2 + i0 + h * 8);
        #pragma unroll
        for (int j = 0; j < 8; ++j)
            out[i0 + h * 8 + j] = (float)(_Float16)(
                w0 * (float)a[j] + w1 * (float)b[j] + w2 * (float)c[j]);
    }
}

// ---------------------------------------------------------------------------
// 4 launches. Buffer plan (no d_ws; stream-ordered liveness, no aliasing
// within any single launch; ALL extents verified against buffer sizes):
//   d_out  = 8,388,608 B. Qf16 [0, 4MiB) + KT8 [4MiB, 8MiB). Exact fit.
//   L1 proj_qk: reads d_in[0] (q), d_in[1] (k); writes d_out only.
//   L2 proj_v:  reads d_in[2] (v); writes VT8 -> d_in[1][0,4MiB) (k_in dead).
//   L3 attn_part: reads KT8/VT8/Qf16; p0 -> d_in[2][0,4MiB), p1 ->
//               d_in[2][4MiB,8MiB) (v_in dead); p2 -> d_in[0][0,4MiB) and
//               stats -> d_in[0][4MiB,+768KiB) (q_in dead; d_in[0]=8.4MB).
//   L4 combine -> d_out f32 (Qf16/KT8 dead).
// ---------------------------------------------------------------------------
extern "C" void kernel_launch(void* const* d_in, const int* in_sizes, int n_in,
                              void* d_out, int out_size, void* d_ws, size_t ws_size,
                              hipStream_t stream) {
    const float* q_in = (const float*)d_in[0];
    const float* k_in = (const float*)d_in[1];
    const float* v_in = (const float*)d_in[2];
    const float* Wq   = (const float*)d_in[3];
    const float* bq   = (const float*)d_in[4];
    const float* Wk   = (const float*)d_in[5];
    const float* bk   = (const float*)d_in[6];
    const float* Wv   = (const float*)d_in[7];
    const float* bv   = (const float*)d_in[8];
    float* out = (float*)d_out;

    _Float16* Qf16  = (_Float16*)d_out;                        // 4 MiB exact
    _Float16* KT8   = (_Float16*)((char*)d_out + (4u << 20));  // 4 MiB exact
    _Float16* VT8   = (_Float16*)d_in[1];                      // 4 MiB
    _Float16* part0 = (_Float16*)d_in[2];                      // 4 MiB
    _Float16* part1 = part0 + (long)2 * 1024 * 1024;           // +4 MiB
    _Float16* part2 = (_Float16*)d_in[0];                      // 4 MiB
    float*    stats = (float*)((char*)d_in[0] + (4u << 20));   // 768 KiB

    proj_qk<<<512, 256, 0, stream>>>(q_in, k_in, Wq, bq, Wk, bk, Qf16, KT8);
    proj_v<<<256, 256, 0, stream>>>(v_in, Wv, bv, VT8);
    attn_part<<<16 * 32 * NSPLIT, 256, 0, stream>>>(KT8, VT8, Qf16,
                                                    part0, part1, part2, stats);
    attn_combine<<<512, 256, 0, stream>>>(part0, part1, part2, stats, out);
}

// Round 8
// 133.323 us; speedup vs baseline: 1.0467x; 1.0467x over previous
//
#include <hip/hip_runtime.h>

// Problem constants (B=2, S=2048, H=8, E=64).
// Harness passes f16 tensors upcast to FLOAT32 (in and out). Internally f16
// compute (lossless re-narrowing of f16-origin data), fp32 MFMA accumulation.
#define S_LEN 2048
#define NH    8
#define EMB   64
#define BM    64    // q rows per block (16 per wave)
#define BN    64    // kv tile length (best measured: R3/R6 config)
#define NKT   (S_LEN / BN)          // 32 kv tiles
#define NSPLIT 2    // KV splits: 16 bh x 32 qt x 2 = 1024 blocks = 4/CU exactly
#define M_INIT  (-1.0e4f)
#define EXP_CLAMP (-80.0f)
#define DEFER_THR 8.0f   // T13: skip rescale while max growth <= 8 (P <= e^8, f16-safe)

typedef _Float16 half8   __attribute__((ext_vector_type(8)));
typedef _Float16 half4   __attribute__((ext_vector_type(4)));
typedef float    float4_t __attribute__((ext_vector_type(4)));
typedef float    float8_t __attribute__((ext_vector_type(8)));

__device__ inline half8 cvt8(const float* p) {
    float8_t f = *reinterpret_cast<const float8_t*>(p);
    half8 h;
    #pragma unroll
    for (int j = 0; j < 8; ++j) h[j] = (_Float16)f[j];
    return h;
}

// async global->LDS, 16B per lane; LDS dest = uniform base + lane*16
__device__ inline void gload_lds16(const _Float16* g, _Float16* l) {
    __builtin_amdgcn_global_load_lds(
        (const __attribute__((address_space(1))) void*)g,
        (__attribute__((address_space(3))) void*)l, 16, 0, 0);
}

// ---------------------------------------------------------------------------
// Projection worker: one segment per 256 blocks.
//   mode 0: Q -> Qf16[bh][s][e], f16, pre-scaled by 0.125
//   mode 1: K -> KT8[bh][f/8][s][f%8]
//   mode 2: V -> VT8[bh][s/8][f][s%8]
// ---------------------------------------------------------------------------
__device__ inline void proj_body(
    int mode, int bid, const float* __restrict__ X,
    const float* __restrict__ W, const float* __restrict__ bias,
    _Float16* __restrict__ Dst)
{
    const int tid  = threadIdx.x;
    const int lane = tid & 63;
    const int wave = tid >> 6;
    const int l15  = lane & 15;
    const int quad = lane >> 4;
    const int gwave = bid * 4 + wave;

    half8 wf[4][2];
    #pragma unroll
    for (int ft = 0; ft < 4; ++ft)
        #pragma unroll
        for (int ks = 0; ks < 2; ++ks)
            wf[ft][ks] = cvt8(W + (ft * 16 + l15) * 64 + ks * 32 + quad * 8);
    float bv[4];
    #pragma unroll
    for (int ft = 0; ft < 4; ++ft) bv[ft] = bias[ft * 16 + l15];

    #pragma unroll
    for (int rt2 = 0; rt2 < 2; ++rt2) {
        const int rt = gwave * 2 + rt2;
        const int arow = rt * 16 + l15;
        half8 xf[2];
        #pragma unroll
        for (int ks = 0; ks < 2; ++ks)
            xf[ks] = cvt8(X + (long)arow * 64 + ks * 32 + quad * 8);
        float4_t acc[4];
        #pragma unroll
        for (int ft = 0; ft < 4; ++ft) {
            acc[ft] = (float4_t){0.f, 0.f, 0.f, 0.f};
            #pragma unroll
            for (int ks = 0; ks < 2; ++ks)
                acc[ft] = __builtin_amdgcn_mfma_f32_16x16x32_f16(
                    xf[ks], wf[ft][ks], acc[ft], 0, 0, 0);
        }
        #pragma unroll
        for (int r = 0; r < 4; ++r) {
            const int row = rt * 16 + quad * 4 + r;     // (b*S+s)*H+h
            const int b = row >> 14;
            const int s = (row >> 3) & 2047;
            const int h = row & 7;
            const int bh = b * NH + h;
            #pragma unroll
            for (int ft = 0; ft < 4; ++ft) {
                const _Float16 v = (_Float16)(acc[ft][r] + bv[ft]);
                const int f = ft * 16 + l15;
                if (mode == 0)
                    Dst[((long)bh * S_LEN + s) * EMB + f] = v * (_Float16)0.125f;
                else if (mode == 1)
                    Dst[(((long)bh * 8 + (f >> 3)) * S_LEN + s) * 8 + (f & 7)] = v;
                else
                    Dst[(((long)bh * 256 + (s >> 3)) * 64 + f) * 8 + (s & 7)] = v;
            }
        }
    }
}

// Launch 1 (512 blocks): seg 0 = Q -> Qf16 (d_out[0,4MiB)), seg 1 = K -> KT8
// (d_out[4MiB,8MiB)). Both are EXACTLY 4,194,304 B; d_out is 8,388,608 B.
__global__ __launch_bounds__(256) void proj_qk(
    const float* __restrict__ q_in, const float* __restrict__ k_in,
    const float* __restrict__ Wq, const float* __restrict__ bq,
    const float* __restrict__ Wk, const float* __restrict__ bk,
    _Float16* __restrict__ Qf16, _Float16* __restrict__ KT8)
{
    const int seg = blockIdx.x >> 8;
    const int bid = blockIdx.x & 255;
    if (seg == 0) proj_body(0, bid, q_in, Wq, bq, Qf16);
    else          proj_body(1, bid, k_in, Wk, bk, KT8);
}

// Launch 2 (256 blocks): V -> VT8 (in d_in[1]; k_in dead after launch 1).
__global__ __launch_bounds__(256) void proj_v(
    const float* __restrict__ v_in,
    const float* __restrict__ Wv, const float* __restrict__ bv_,
    _Float16* __restrict__ VT8)
{
    proj_body(2, blockIdx.x, v_in, Wv, bv_, VT8);
}

// ---------------------------------------------------------------------------
// Launch 3: flash attention partials. KV-split=2, S^T orientation, BN=64.
// R8 = R6 (verified best, 137.5) with ONE chain cut: the P LDS round-trip is
// exposed once per tile instead of twice — write ALL 4 half4 P stores, ONE
// lgkmcnt wait, read BOTH half8 A-frags, then the full 20-MFMA PV+l burst in
// a single setprio region. (R6 did write/wait/read/MFMA per ts = 2 exposed
// LDS round-trips.) Structural experiments R4 (6 blocks/CU) and R7 (skewed
// pipeline, 3 blocks/CU) both regressed; this keeps R6's schedule exactly.
// Kept (verified): f16 Q direct loads, ones-MFMA l, max3 tree, T13 defer-max
// zero-crosslane common path, T5 setprio, XCD swizzle, P XOR-swizzle.
// ---------------------------------------------------------------------------
__global__ __launch_bounds__(256, 4) void attn_part(
    const _Float16* __restrict__ KT, const _Float16* __restrict__ VT,
    const _Float16* __restrict__ Qf16,
    _Float16* __restrict__ p0, _Float16* __restrict__ p1,
    float* __restrict__ stats)
{
    __shared__ __align__(16) _Float16 Kb[2][8 * 64 * 8];   // 2 x 8 KB [ec][tl][ej]
    __shared__ __align__(16) _Float16 Vb[2][8 * 64 * 8];   // 2 x 8 KB [tc][e][tj]
    __shared__ __align__(16) _Float16 Pl[4][16 * 64];      // 8 KB per-wave P (swizzled)

    const int tid  = threadIdx.x;
    const int lane = tid & 63;
    const int wave = tid >> 6;
    const int l15  = lane & 15;
    const int quad = lane >> 4;

    // XCD-aware decomposition: 1024 = 8 XCD * (2 heads * 64 blocks)
    const int bx     = blockIdx.x;
    const int xcd    = bx & 7;
    const int j      = bx >> 3;             // 0..127 within this XCD
    const int hh     = j >> 6;              // which of the 2 heads here
    const int within = j & 63;              // qt*NSPLIT + sp
    const int bh     = xcd * 2 + hh;
    const int qt     = within >> 1;
    const int sp     = within & 1;

    const int qrow0 = qt * BM + wave * 16;
    const _Float16* kg  = KT + (long)bh * 8 * S_LEN * 8;  // head base in KT8
    const _Float16* vgh = VT + (long)bh * 256 * 512;      // head base in VT8

    // per-thread staging bases (constant per-tile offsets added in loop)
    const _Float16* k0 = kg + ((long)(tid >> 6) * S_LEN + (tid & 63)) * 8;
    const _Float16* k1 = kg + ((long)((tid >> 6) + 4) * S_LEN + (tid & 63)) * 8;
    const _Float16* v0 = vgh + tid * 8;
    const _Float16* v1 = vgh + (256 + tid) * 8;

    const int kb = sp * (NKT / NSPLIT), ke = kb + (NKT / NSPLIT);  // 16 tiles

    // ---- prologue: stage tile kb into buffer 0; load Q frags meanwhile ----
    {
        const long t8  = (long)(kb * BN) * 8;
        const long t64 = (long)(kb * BN) * 64;
        gload_lds16(k0 + t8,  &Kb[0][tid * 8]);
        gload_lds16(k1 + t8,  &Kb[0][(256 + tid) * 8]);
        gload_lds16(v0 + t64, &Vb[0][tid * 8]);
        gload_lds16(v1 + t64, &Vb[0][(256 + tid) * 8]);
    }

    half8 qf[2];   // B-frag: Q[n = q-row l15][e = ks*32+quad*8+j] (f16 direct)
    {
        const _Float16* qrow = Qf16 + ((long)bh * S_LEN + qrow0 + l15) * EMB;
        qf[0] = *reinterpret_cast<const half8*>(qrow + quad * 8);
        qf[1] = *reinterpret_cast<const half8*>(qrow + 32 + quad * 8);
    }

    half8 vones;   // B-frag of all-ones for the l row-sum MFMA
    #pragma unroll
    for (int jj = 0; jj < 8; ++jj) vones[jj] = (_Float16)1.0f;

    float4_t o[4];
    #pragma unroll
    for (int et = 0; et < 4; ++et) o[et] = (float4_t){0.f, 0.f, 0.f, 0.f};
    float4_t lacc = (float4_t){0.f, 0.f, 0.f, 0.f};  // P row-sums, rows quad*4+r
    float m_run = M_INIT;      // running (possibly stale) max for q-row l15

    const int pswz = (l15 & 7) << 3;      // P column XOR-swizzle
    _Float16* Pw = Pl[wave];

    __syncthreads();                      // drains prologue vmcnt -> tile kb ready

    for (int kt = kb; kt < ke; ++kt) {
        const int cur = (kt - kb) & 1;
        const bool more = (kt + 1 < ke);

        // ---- issue next tile's staging into the other buffer (overlapped) ----
        if (more) {
            const long t8  = (long)((kt + 1) * BN) * 8;
            const long t64 = (long)((kt + 1) * BN) * 64;
            _Float16* kd = Kb[cur ^ 1];
            _Float16* vd = Vb[cur ^ 1];
            gload_lds16(k0 + t8,  kd + tid * 8);
            gload_lds16(k1 + t8,  kd + (256 + tid) * 8);
            gload_lds16(v0 + t64, vd + tid * 8);
            gload_lds16(v1 + t64, vd + (256 + tid) * 8);
        }

        const _Float16* Kc = Kb[cur];
        const _Float16* Vc = Vb[cur];

        // ---- S^T = K Q^T : 4 n-tiles of 16 t-rows ----
        float4_t sacc[4];
        #pragma unroll
        for (int nt = 0; nt < 4; ++nt) sacc[nt] = (float4_t){0.f, 0.f, 0.f, 0.f};
        __builtin_amdgcn_s_setprio(1);
        #pragma unroll
        for (int nt = 0; nt < 4; ++nt)
            #pragma unroll
            for (int ks = 0; ks < 2; ++ks) {
                half8 kf = *reinterpret_cast<const half8*>(   // A: K[m=t][e]
                    Kc + (ks * 4 + quad) * 512 + (nt * 16 + l15) * 8);
                sacc[nt] = __builtin_amdgcn_mfma_f32_16x16x32_f16(
                    kf, qf[ks], sacc[nt], 0, 0, 0);
            }
        __builtin_amdgcn_s_setprio(0);

        // ---- local max of this lane's 16 values (fused max3 tree) ----
        float mx = fmaxf(fmaxf(sacc[0][0], sacc[0][1]),
                         fmaxf(sacc[0][2], sacc[0][3]));
        mx = fmaxf(fmaxf(mx, sacc[1][0]), sacc[1][1]);
        mx = fmaxf(fmaxf(mx, sacc[1][2]), sacc[1][3]);
        mx = fmaxf(fmaxf(mx, sacc[2][0]), sacc[2][1]);
        mx = fmaxf(fmaxf(mx, sacc[2][2]), sacc[2][3]);
        mx = fmaxf(fmaxf(mx, sacc[3][0]), sacc[3][1]);
        mx = fmaxf(fmaxf(mx, sacc[3][2]), sacc[3][3]);

        // T13 defer: wave-wide vote covers every row's every value, so m_run
        // stays a valid (stale) bound when no lane exceeds THR.
        if (!__all(mx - m_run <= DEFER_THR)) {
            float mr = fmaxf(mx, __shfl_xor(mx, 16));
            mr = fmaxf(mr, __shfl_xor(mr, 32));
            const float mn = fmaxf(m_run, mr);
            const float alpha = __expf(fmaxf(m_run - mn, EXP_CLAMP));
            m_run = mn;
            #pragma unroll
            for (int r = 0; r < 4; ++r) {  // o/lacc rows are quad*4+r
                const float ar = __shfl(alpha, quad * 4 + r);
                lacc[r] *= ar;
                #pragma unroll
                for (int et = 0; et < 4; ++et) o[et][r] *= ar;
            }
        }

        // ---- exp + ALL P stores first -> ONE LDS wait -> both A-frags ----
        #pragma unroll
        for (int nt = 0; nt < 4; ++nt) {
            half4 ph;
            #pragma unroll
            for (int r = 0; r < 4; ++r)
                ph[r] = (_Float16)__expf(sacc[nt][r] - m_run);
            *reinterpret_cast<half4*>(
                &Pw[l15 * 64 + ((nt * 16 + quad * 4) ^ pswz)]) = ph;
        }
        // Both reads issue together: single write->read round-trip exposed.
        half8 pf0 = *reinterpret_cast<const half8*>(
            &Pw[l15 * 64 + ((quad * 8) ^ pswz)]);
        half8 pf1 = *reinterpret_cast<const half8*>(
            &Pw[l15 * 64 + ((32 + quad * 8) ^ pswz)]);

        // ---- PV + l: 20 MFMAs in one burst (V-frag reads overlap MFMAs) ----
        __builtin_amdgcn_s_setprio(1);
        #pragma unroll
        for (int et = 0; et < 4; ++et) {
            half8 vf = *reinterpret_cast<const half8*>(
                Vc + quad * 512 + (et * 16 + l15) * 8);
            o[et] = __builtin_amdgcn_mfma_f32_16x16x32_f16(pf0, vf, o[et], 0, 0, 0);
        }
        lacc = __builtin_amdgcn_mfma_f32_16x16x32_f16(pf0, vones, lacc, 0, 0, 0);
        #pragma unroll
        for (int et = 0; et < 4; ++et) {
            half8 vf = *reinterpret_cast<const half8*>(
                Vc + (4 + quad) * 512 + (et * 16 + l15) * 8);
            o[et] = __builtin_amdgcn_mfma_f32_16x16x32_f16(pf1, vf, o[et], 0, 0, 0);
        }
        lacc = __builtin_amdgcn_mfma_f32_16x16x32_f16(pf1, vones, lacc, 0, 0, 0);
        __builtin_amdgcn_s_setprio(0);

        // one barrier per tile: compiler drains vmcnt here; the prefetch
        // issued at loop top has had the whole compute phase to complete.
        if (more) __syncthreads();
    }

    // ---- epilogue: lacc[r] IS the row sum for row quad*4+r (no shuffles) ----
    _Float16* pp = (sp == 0) ? p0 : p1;
    #pragma unroll
    for (int r = 0; r < 4; ++r) {
        const float inv = 1.f / lacc[r];
        const int row = qrow0 + quad * 4 + r;            // 0..2047 within head
        const int R = bh * S_LEN + row;                  // 0..32767 global row
        #pragma unroll
        for (int et = 0; et < 4; ++et)
            pp[(long)R * EMB + et * 16 + l15] = (_Float16)(o[et][r] * inv);
    }
    // stats: lane i (<16) owns q-row i. l for row=lane lives at quad lane>>2,
    // component lane&3 (uniform across l15) -> 4 shuffles + select.
    {
        const int srcl = (lane >> 2) * 16;
        const float s0 = __shfl(lacc[0], srcl);
        const float s1 = __shfl(lacc[1], srcl);
        const float s2 = __shfl(lacc[2], srcl);
        const float s3 = __shfl(lacc[3], srcl);
        const int rr = lane & 3;
        const float lsel = (rr == 0) ? s0 : (rr == 1) ? s1 : (rr == 2) ? s2 : s3;
        if (lane < 16) {
            const int R = bh * S_LEN + qrow0 + lane;
            stats[sp * 32768 + R] = m_run;
            stats[(NSPLIT + sp) * 32768 + R] = lsel;
        }
    }
}

// ---------------------------------------------------------------------------
// Launch 4: combine the 2 partials. O = sum w_i*Ohat_i, f16-round, f32 store.
// Stale-m partials are exact here: w_i = l_i * exp(m_i - M) is invariant.
// ---------------------------------------------------------------------------
__global__ __launch_bounds__(256) void attn_combine(
    const _Float16* __restrict__ p0, const _Float16* __restrict__ p1,
    const float* __restrict__ stats, float* __restrict__ out)
{
    const int gid = blockIdx.x * 256 + threadIdx.x;      // 131072 threads
    const int R  = gid >> 2;
    const int c0 = (gid & 3) * 16;
    const float m0 = stats[R], m1 = stats[32768 + R];
    const float l0 = stats[2 * 32768 + R], l1 = stats[3 * 32768 + R];
    const float M = fmaxf(m0, m1);
    float w0 = l0 * __expf(fmaxf(m0 - M, EXP_CLAMP));
    float w1 = l1 * __expf(fmaxf(m1 - M, EXP_CLAMP));
    const float rinv = 1.f / (w0 + w1);
    w0 *= rinv; w1 *= rinv;
    const long i0 = (long)R * EMB + c0;
    #pragma unroll
    for (int h = 0; h < 2; ++h) {
        half8 a = *reinterpret_cast<const half8*>(p0 + i0 + h * 8);
        half8 b = *reinterpret_cast<const half8*>(p1 + i0 + h * 8);
        #pragma unroll
        for (int j = 0; j < 8; ++j)
            out[i0 + h * 8 + j] = (float)(_Float16)(
                w0 * (float)a[j] + w1 * (float)b[j]);
    }
}

// ---------------------------------------------------------------------------
// 4 launches. Buffer plan (no d_ws; stream-ordered liveness, no aliasing
// within any single launch; ALL extents verified against buffer sizes):
//   d_out  = 8,388,608 B. Qf16 [0, 4MiB) + KT8 [4MiB, 8MiB). Exact fit.
//   L1 proj_qk: reads d_in[0] (q), d_in[1] (k); writes d_out only.
//   L2 proj_v:  reads d_in[2] (v); writes VT8 -> d_in[1][0,4MiB) (k_in dead).
//   L3 attn_part: reads KT8/VT8/Qf16; p0 -> d_in[2][0,4MiB), p1 ->
//               d_in[2][4MiB,8MiB) (v_in dead); stats -> d_in[0][0,512KiB)
//               (q_in dead).
//   L4 combine -> d_out f32 (Qf16/KT8 dead).
// ---------------------------------------------------------------------------
extern "C" void kernel_launch(void* const* d_in, const int* in_sizes, int n_in,
                              void* d_out, int out_size, void* d_ws, size_t ws_size,
                              hipStream_t stream) {
    const float* q_in = (const float*)d_in[0];
    const float* k_in = (const float*)d_in[1];
    const float* v_in = (const float*)d_in[2];
    const float* Wq   = (const float*)d_in[3];
    const float* bq   = (const float*)d_in[4];
    const float* Wk   = (const float*)d_in[5];
    const float* bk   = (const float*)d_in[6];
    const float* Wv   = (const float*)d_in[7];
    const float* bv   = (const float*)d_in[8];
    float* out = (float*)d_out;

    _Float16* Qf16  = (_Float16*)d_out;                        // 4 MiB exact
    _Float16* KT8   = (_Float16*)((char*)d_out + (4u << 20));  // 4 MiB exact
    _Float16* VT8   = (_Float16*)d_in[1];                      // 4 MiB
    _Float16* part0 = (_Float16*)d_in[2];                      // 4 MiB
    _Float16* part1 = part0 + (long)2 * 1024 * 1024;           // +4 MiB
    float*    stats = (float*)d_in[0];                         // 512 KiB

    proj_qk<<<512, 256, 0, stream>>>(q_in, k_in, Wq, bq, Wk, bk, Qf16, KT8);
    proj_v<<<256, 256, 0, stream>>>(v_in, Wv, bv, VT8);
    attn_part<<<16 * 32 * NSPLIT, 256, 0, stream>>>(KT8, VT8, Qf16,
                                                    part0, part1, stats);
    attn_combine<<<512, 256, 0, stream>>>(part0, part1, stats, out);
}

// Round 9
// 130.537 us; speedup vs baseline: 1.0690x; 1.0213x over previous
//
#include <hip/hip_runtime.h>

// Problem constants (B=2, S=2048, H=8, E=64).
// Harness passes f16 tensors upcast to FLOAT32 (in and out). Internally f16
// compute (lossless re-narrowing of f16-origin data), fp32 MFMA accumulation.
#define S_LEN 2048
#define NH    8
#define EMB   64
#define BM    64    // q rows per block (16 per wave)
#define BN    64    // kv tile length (best measured: R3/R6/R8 config)
#define NKT   (S_LEN / BN)          // 32 kv tiles
#define NSPLIT 2    // KV splits: 16 bh x 32 qt x 2 = 1024 blocks = 4/CU exactly
#define M_INIT  (-1.0e4f)
#define EXP_CLAMP (-80.0f)
#define DEFER_THR 8.0f   // T13: skip rescale while max growth <= 8 (P <= e^8, f16-safe)

typedef _Float16 half8   __attribute__((ext_vector_type(8)));
typedef _Float16 half4   __attribute__((ext_vector_type(4)));
typedef float    float4_t __attribute__((ext_vector_type(4)));
typedef float    float8_t __attribute__((ext_vector_type(8)));

__device__ inline half8 cvt8(const float* p) {
    float8_t f = *reinterpret_cast<const float8_t*>(p);
    half8 h;
    #pragma unroll
    for (int j = 0; j < 8; ++j) h[j] = (_Float16)f[j];
    return h;
}

// async global->LDS, 16B per lane; LDS dest = uniform base + lane*16
__device__ inline void gload_lds16(const _Float16* g, _Float16* l) {
    __builtin_amdgcn_global_load_lds(
        (const __attribute__((address_space(1))) void*)g,
        (__attribute__((address_space(3))) void*)l, 16, 0, 0);
}

// ---------------------------------------------------------------------------
// Projection worker: one segment per 256 blocks.
//   mode 0: Q -> Qf16[bh][s][e], f16, pre-scaled by 0.125
//   mode 1: K -> KT8[bh][f/8][s][f%8]
//   mode 2: V -> VT8[bh][s/8][f][s%8]
// ---------------------------------------------------------------------------
__device__ inline void proj_body(
    int mode, int bid, const float* __restrict__ X,
    const float* __restrict__ W, const float* __restrict__ bias,
    _Float16* __restrict__ Dst)
{
    const int tid  = threadIdx.x;
    const int lane = tid & 63;
    const int wave = tid >> 6;
    const int l15  = lane & 15;
    const int quad = lane >> 4;
    const int gwave = bid * 4 + wave;

    half8 wf[4][2];
    #pragma unroll
    for (int ft = 0; ft < 4; ++ft)
        #pragma unroll
        for (int ks = 0; ks < 2; ++ks)
            wf[ft][ks] = cvt8(W + (ft * 16 + l15) * 64 + ks * 32 + quad * 8);
    float bv[4];
    #pragma unroll
    for (int ft = 0; ft < 4; ++ft) bv[ft] = bias[ft * 16 + l15];

    #pragma unroll
    for (int rt2 = 0; rt2 < 2; ++rt2) {
        const int rt = gwave * 2 + rt2;
        const int arow = rt * 16 + l15;
        half8 xf[2];
        #pragma unroll
        for (int ks = 0; ks < 2; ++ks)
            xf[ks] = cvt8(X + (long)arow * 64 + ks * 32 + quad * 8);
        float4_t acc[4];
        #pragma unroll
        for (int ft = 0; ft < 4; ++ft) {
            acc[ft] = (float4_t){0.f, 0.f, 0.f, 0.f};
            #pragma unroll
            for (int ks = 0; ks < 2; ++ks)
                acc[ft] = __builtin_amdgcn_mfma_f32_16x16x32_f16(
                    xf[ks], wf[ft][ks], acc[ft], 0, 0, 0);
        }
        #pragma unroll
        for (int r = 0; r < 4; ++r) {
            const int row = rt * 16 + quad * 4 + r;     // (b*S+s)*H+h
            const int b = row >> 14;
            const int s = (row >> 3) & 2047;
            const int h = row & 7;
            const int bh = b * NH + h;
            #pragma unroll
            for (int ft = 0; ft < 4; ++ft) {
                const _Float16 v = (_Float16)(acc[ft][r] + bv[ft]);
                const int f = ft * 16 + l15;
                if (mode == 0)
                    Dst[((long)bh * S_LEN + s) * EMB + f] = v * (_Float16)0.125f;
                else if (mode == 1)
                    Dst[(((long)bh * 8 + (f >> 3)) * S_LEN + s) * 8 + (f & 7)] = v;
                else
                    Dst[(((long)bh * 256 + (s >> 3)) * 64 + f) * 8 + (s & 7)] = v;
            }
        }
    }
}

// Fused projection launch (768 blocks): seg 0 = Q -> Qf16 (d_out[0,4MiB)),
// seg 1 = K -> KT8 (d_out[4MiB,8MiB)), seg 2 = V -> VT8 (d_ws).
// No input buffer is written by any segment -> no intra-launch hazards.
__global__ __launch_bounds__(256) void proj_qkv(
    const float* __restrict__ q_in, const float* __restrict__ k_in,
    const float* __restrict__ v_in,
    const float* __restrict__ Wq, const float* __restrict__ bq,
    const float* __restrict__ Wk, const float* __restrict__ bk,
    const float* __restrict__ Wv, const float* __restrict__ bv_,
    _Float16* __restrict__ Qf16, _Float16* __restrict__ KT8,
    _Float16* __restrict__ VT8)
{
    const int seg = blockIdx.x >> 8;
    const int bid = blockIdx.x & 255;
    if (seg == 0)      proj_body(0, bid, q_in, Wq, bq, Qf16);
    else if (seg == 1) proj_body(1, bid, k_in, Wk, bk, KT8);
    else               proj_body(2, bid, v_in, Wv, bv_, VT8);
}

// Fallback (ws_size too small): R8's two-launch plan.
__global__ __launch_bounds__(256) void proj_qk(
    const float* __restrict__ q_in, const float* __restrict__ k_in,
    const float* __restrict__ Wq, const float* __restrict__ bq,
    const float* __restrict__ Wk, const float* __restrict__ bk,
    _Float16* __restrict__ Qf16, _Float16* __restrict__ KT8)
{
    const int seg = blockIdx.x >> 8;
    const int bid = blockIdx.x & 255;
    if (seg == 0) proj_body(0, bid, q_in, Wq, bq, Qf16);
    else          proj_body(1, bid, k_in, Wk, bk, KT8);
}

__global__ __launch_bounds__(256) void proj_v(
    const float* __restrict__ v_in,
    const float* __restrict__ Wv, const float* __restrict__ bv_,
    _Float16* __restrict__ VT8)
{
    proj_body(2, blockIdx.x, v_in, Wv, bv_, VT8);
}

// ---------------------------------------------------------------------------
// Launch 2: flash attention partials. KV-split=2, S^T orientation, BN=64.
// Byte-identical schedule to R8 (verified best, 133.3): one barrier per tile,
// double-buffered K/V via global_load_lds, single-exposed P LDS round-trip
// (write all 4 half4 -> one wait -> both A-frags -> 20-MFMA burst), f16 Q
// direct loads, ones-MFMA l, max3 tree, T13 defer-max, T5 setprio, XCD
// swizzle, P XOR-swizzle.
// ---------------------------------------------------------------------------
__global__ __launch_bounds__(256, 4) void attn_part(
    const _Float16* __restrict__ KT, const _Float16* __restrict__ VT,
    const _Float16* __restrict__ Qf16,
    _Float16* __restrict__ p0, _Float16* __restrict__ p1,
    float* __restrict__ stats)
{
    __shared__ __align__(16) _Float16 Kb[2][8 * 64 * 8];   // 2 x 8 KB [ec][tl][ej]
    __shared__ __align__(16) _Float16 Vb[2][8 * 64 * 8];   // 2 x 8 KB [tc][e][tj]
    __shared__ __align__(16) _Float16 Pl[4][16 * 64];      // 8 KB per-wave P (swizzled)

    const int tid  = threadIdx.x;
    const int lane = tid & 63;
    const int wave = tid >> 6;
    const int l15  = lane & 15;
    const int quad = lane >> 4;

    // XCD-aware decomposition: 1024 = 8 XCD * (2 heads * 64 blocks)
    const int bx     = blockIdx.x;
    const int xcd    = bx & 7;
    const int j      = bx >> 3;             // 0..127 within this XCD
    const int hh     = j >> 6;              // which of the 2 heads here
    const int within = j & 63;              // qt*NSPLIT + sp
    const int bh     = xcd * 2 + hh;
    const int qt     = within >> 1;
    const int sp     = within & 1;

    const int qrow0 = qt * BM + wave * 16;
    const _Float16* kg  = KT + (long)bh * 8 * S_LEN * 8;  // head base in KT8
    const _Float16* vgh = VT + (long)bh * 256 * 512;      // head base in VT8

    // per-thread staging bases (constant per-tile offsets added in loop)
    const _Float16* k0 = kg + ((long)(tid >> 6) * S_LEN + (tid & 63)) * 8;
    const _Float16* k1 = kg + ((long)((tid >> 6) + 4) * S_LEN + (tid & 63)) * 8;
    const _Float16* v0 = vgh + tid * 8;
    const _Float16* v1 = vgh + (256 + tid) * 8;

    const int kb = sp * (NKT / NSPLIT), ke = kb + (NKT / NSPLIT);  // 16 tiles

    // ---- prologue: stage tile kb into buffer 0; load Q frags meanwhile ----
    {
        const long t8  = (long)(kb * BN) * 8;
        const long t64 = (long)(kb * BN) * 64;
        gload_lds16(k0 + t8,  &Kb[0][tid * 8]);
        gload_lds16(k1 + t8,  &Kb[0][(256 + tid) * 8]);
        gload_lds16(v0 + t64, &Vb[0][tid * 8]);
        gload_lds16(v1 + t64, &Vb[0][(256 + tid) * 8]);
    }

    half8 qf[2];   // B-frag: Q[n = q-row l15][e = ks*32+quad*8+j] (f16 direct)
    {
        const _Float16* qrow = Qf16 + ((long)bh * S_LEN + qrow0 + l15) * EMB;
        qf[0] = *reinterpret_cast<const half8*>(qrow + quad * 8);
        qf[1] = *reinterpret_cast<const half8*>(qrow + 32 + quad * 8);
    }

    half8 vones;   // B-frag of all-ones for the l row-sum MFMA
    #pragma unroll
    for (int jj = 0; jj < 8; ++jj) vones[jj] = (_Float16)1.0f;

    float4_t o[4];
    #pragma unroll
    for (int et = 0; et < 4; ++et) o[et] = (float4_t){0.f, 0.f, 0.f, 0.f};
    float4_t lacc = (float4_t){0.f, 0.f, 0.f, 0.f};  // P row-sums, rows quad*4+r
    float m_run = M_INIT;      // running (possibly stale) max for q-row l15

    const int pswz = (l15 & 7) << 3;      // P column XOR-swizzle
    _Float16* Pw = Pl[wave];

    __syncthreads();                      // drains prologue vmcnt -> tile kb ready

    for (int kt = kb; kt < ke; ++kt) {
        const int cur = (kt - kb) & 1;
        const bool more = (kt + 1 < ke);

        // ---- issue next tile's staging into the other buffer (overlapped) ----
        if (more) {
            const long t8  = (long)((kt + 1) * BN) * 8;
            const long t64 = (long)((kt + 1) * BN) * 64;
            _Float16* kd = Kb[cur ^ 1];
            _Float16* vd = Vb[cur ^ 1];
            gload_lds16(k0 + t8,  kd + tid * 8);
            gload_lds16(k1 + t8,  kd + (256 + tid) * 8);
            gload_lds16(v0 + t64, vd + tid * 8);
            gload_lds16(v1 + t64, vd + (256 + tid) * 8);
        }

        const _Float16* Kc = Kb[cur];
        const _Float16* Vc = Vb[cur];

        // ---- S^T = K Q^T : 4 n-tiles of 16 t-rows ----
        float4_t sacc[4];
        #pragma unroll
        for (int nt = 0; nt < 4; ++nt) sacc[nt] = (float4_t){0.f, 0.f, 0.f, 0.f};
        __builtin_amdgcn_s_setprio(1);
        #pragma unroll
        for (int nt = 0; nt < 4; ++nt)
            #pragma unroll
            for (int ks = 0; ks < 2; ++ks) {
                half8 kf = *reinterpret_cast<const half8*>(   // A: K[m=t][e]
                    Kc + (ks * 4 + quad) * 512 + (nt * 16 + l15) * 8);
                sacc[nt] = __builtin_amdgcn_mfma_f32_16x16x32_f16(
                    kf, qf[ks], sacc[nt], 0, 0, 0);
            }
        __builtin_amdgcn_s_setprio(0);

        // ---- local max of this lane's 16 values (fused max3 tree) ----
        float mx = fmaxf(fmaxf(sacc[0][0], sacc[0][1]),
                         fmaxf(sacc[0][2], sacc[0][3]));
        mx = fmaxf(fmaxf(mx, sacc[1][0]), sacc[1][1]);
        mx = fmaxf(fmaxf(mx, sacc[1][2]), sacc[1][3]);
        mx = fmaxf(fmaxf(mx, sacc[2][0]), sacc[2][1]);
        mx = fmaxf(fmaxf(mx, sacc[2][2]), sacc[2][3]);
        mx = fmaxf(fmaxf(mx, sacc[3][0]), sacc[3][1]);
        mx = fmaxf(fmaxf(mx, sacc[3][2]), sacc[3][3]);

        // T13 defer: wave-wide vote covers every row's every value, so m_run
        // stays a valid (stale) bound when no lane exceeds THR.
        if (!__all(mx - m_run <= DEFER_THR)) {
            float mr = fmaxf(mx, __shfl_xor(mx, 16));
            mr = fmaxf(mr, __shfl_xor(mr, 32));
            const float mn = fmaxf(m_run, mr);
            const float alpha = __expf(fmaxf(m_run - mn, EXP_CLAMP));
            m_run = mn;
            #pragma unroll
            for (int r = 0; r < 4; ++r) {  // o/lacc rows are quad*4+r
                const float ar = __shfl(alpha, quad * 4 + r);
                lacc[r] *= ar;
                #pragma unroll
                for (int et = 0; et < 4; ++et) o[et][r] *= ar;
            }
        }

        // ---- exp + ALL P stores first -> ONE LDS wait -> both A-frags ----
        #pragma unroll
        for (int nt = 0; nt < 4; ++nt) {
            half4 ph;
            #pragma unroll
            for (int r = 0; r < 4; ++r)
                ph[r] = (_Float16)__expf(sacc[nt][r] - m_run);
            *reinterpret_cast<half4*>(
                &Pw[l15 * 64 + ((nt * 16 + quad * 4) ^ pswz)]) = ph;
        }
        // Both reads issue together: single write->read round-trip exposed.
        half8 pf0 = *reinterpret_cast<const half8*>(
            &Pw[l15 * 64 + ((quad * 8) ^ pswz)]);
        half8 pf1 = *reinterpret_cast<const half8*>(
            &Pw[l15 * 64 + ((32 + quad * 8) ^ pswz)]);

        // ---- PV + l: 20 MFMAs in one burst (V-frag reads overlap MFMAs) ----
        __builtin_amdgcn_s_setprio(1);
        #pragma unroll
        for (int et = 0; et < 4; ++et) {
            half8 vf = *reinterpret_cast<const half8*>(
                Vc + quad * 512 + (et * 16 + l15) * 8);
            o[et] = __builtin_amdgcn_mfma_f32_16x16x32_f16(pf0, vf, o[et], 0, 0, 0);
        }
        lacc = __builtin_amdgcn_mfma_f32_16x16x32_f16(pf0, vones, lacc, 0, 0, 0);
        #pragma unroll
        for (int et = 0; et < 4; ++et) {
            half8 vf = *reinterpret_cast<const half8*>(
                Vc + (4 + quad) * 512 + (et * 16 + l15) * 8);
            o[et] = __builtin_amdgcn_mfma_f32_16x16x32_f16(pf1, vf, o[et], 0, 0, 0);
        }
        lacc = __builtin_amdgcn_mfma_f32_16x16x32_f16(pf1, vones, lacc, 0, 0, 0);
        __builtin_amdgcn_s_setprio(0);

        // one barrier per tile: compiler drains vmcnt here; the prefetch
        // issued at loop top has had the whole compute phase to complete.
        if (more) __syncthreads();
    }

    // ---- epilogue: lacc[r] IS the row sum for row quad*4+r (no shuffles) ----
    _Float16* pp = (sp == 0) ? p0 : p1;
    #pragma unroll
    for (int r = 0; r < 4; ++r) {
        const float inv = 1.f / lacc[r];
        const int row = qrow0 + quad * 4 + r;            // 0..2047 within head
        const int R = bh * S_LEN + row;                  // 0..32767 global row
        #pragma unroll
        for (int et = 0; et < 4; ++et)
            pp[(long)R * EMB + et * 16 + l15] = (_Float16)(o[et][r] * inv);
    }
    // stats: lane i (<16) owns q-row i. l for row=lane lives at quad lane>>2,
    // component lane&3 (uniform across l15) -> 4 shuffles + select.
    {
        const int srcl = (lane >> 2) * 16;
        const float s0 = __shfl(lacc[0], srcl);
        const float s1 = __shfl(lacc[1], srcl);
        const float s2 = __shfl(lacc[2], srcl);
        const float s3 = __shfl(lacc[3], srcl);
        const int rr = lane & 3;
        const float lsel = (rr == 0) ? s0 : (rr == 1) ? s1 : (rr == 2) ? s2 : s3;
        if (lane < 16) {
            const int R = bh * S_LEN + qrow0 + lane;
            stats[sp * 32768 + R] = m_run;
            stats[(NSPLIT + sp) * 32768 + R] = lsel;
        }
    }
}

// ---------------------------------------------------------------------------
// Launch 3: combine the 2 partials. O = sum w_i*Ohat_i, f16-round, f32 store.
// Stale-m partials are exact here: w_i = l_i * exp(m_i - M) is invariant.
// ---------------------------------------------------------------------------
__global__ __launch_bounds__(256) void attn_combine(
    const _Float16* __restrict__ p0, const _Float16* __restrict__ p1,
    const float* __restrict__ stats, float* __restrict__ out)
{
    const int gid = blockIdx.x * 256 + threadIdx.x;      // 131072 threads
    const int R  = gid >> 2;
    const int c0 = (gid & 3) * 16;
    const float m0 = stats[R], m1 = stats[32768 + R];
    const float l0 = stats[2 * 32768 + R], l1 = stats[3 * 32768 + R];
    const float M = fmaxf(m0, m1);
    float w0 = l0 * __expf(fmaxf(m0 - M, EXP_CLAMP));
    float w1 = l1 * __expf(fmaxf(m1 - M, EXP_CLAMP));
    const float rinv = 1.f / (w0 + w1);
    w0 *= rinv; w1 *= rinv;
    const long i0 = (long)R * EMB + c0;
    #pragma unroll
    for (int h = 0; h < 2; ++h) {
        half8 a = *reinterpret_cast<const half8*>(p0 + i0 + h * 8);
        half8 b = *reinterpret_cast<const half8*>(p1 + i0 + h * 8);
        #pragma unroll
        for (int j = 0; j < 8; ++j)
            out[i0 + h * 8 + j] = (float)(_Float16)(
                w0 * (float)a[j] + w1 * (float)b[j]);
    }
}

// ---------------------------------------------------------------------------
// 3 launches (4 in fallback). Buffer plan (stream-ordered liveness, no
// aliasing within any single launch; ALL extents verified):
//   d_out = 8,388,608 B. Qf16 [0, 4MiB) + KT8 [4MiB, 8MiB). Exact fit.
//   VT8 (4 MiB) -> d_ws[0,4MiB) (harness poisons d_ws anyway; guarded by
//   ws_size check with R8's two-launch fallback writing VT8 to d_in[1]).
//   L1 proj_qkv: reads d_in[0..2]; writes d_out + d_ws only. No hazards.
//   L2 attn_part: reads KT8/VT8/Qf16; p0 -> d_in[2][0,4MiB), p1 ->
//               d_in[2][4MiB,8MiB) (v_in dead); stats -> d_in[0][0,512KiB)
//               (q_in dead).
//   L3 combine -> d_out f32 (Qf16/KT8 dead).
// ---------------------------------------------------------------------------
extern "C" void kernel_launch(void* const* d_in, const int* in_sizes, int n_in,
                              void* d_out, int out_size, void* d_ws, size_t ws_size,
                              hipStream_t stream) {
    const float* q_in = (const float*)d_in[0];
    const float* k_in = (const float*)d_in[1];
    const float* v_in = (const float*)d_in[2];
    const float* Wq   = (const float*)d_in[3];
    const float* bq   = (const float*)d_in[4];
    const float* Wk   = (const float*)d_in[5];
    const float* bk   = (const float*)d_in[6];
    const float* Wv   = (const float*)d_in[7];
    const float* bv   = (const float*)d_in[8];
    float* out = (float*)d_out;

    _Float16* Qf16  = (_Float16*)d_out;                        // 4 MiB exact
    _Float16* KT8   = (_Float16*)((char*)d_out + (4u << 20));  // 4 MiB exact
    _Float16* part0 = (_Float16*)d_in[2];                      // 4 MiB
    _Float16* part1 = part0 + (long)2 * 1024 * 1024;           // +4 MiB
    float*    stats = (float*)d_in[0];                         // 512 KiB

    _Float16* VT8;
    if (ws_size >= (size_t)(4u << 20)) {
        // Fused path: VT8 in workspace -> all three projections in ONE launch
        // (no WAR on d_in[1], no extra dispatch).
        VT8 = (_Float16*)d_ws;
        proj_qkv<<<768, 256, 0, stream>>>(q_in, k_in, v_in, Wq, bq, Wk, bk,
                                          Wv, bv, Qf16, KT8, VT8);
    } else {
        // Fallback (R8 plan): VT8 in d_in[1] after k_in is consumed.
        VT8 = (_Float16*)d_in[1];
        proj_qk<<<512, 256, 0, stream>>>(q_in, k_in, Wq, bq, Wk, bk, Qf16, KT8);
        proj_v<<<256, 256, 0, stream>>>(v_in, Wv, bv, VT8);
    }
    attn_part<<<16 * 32 * NSPLIT, 256, 0, stream>>>(KT8, VT8, Qf16,
                                                    part0, part1, stats);
    attn_combine<<<512, 256, 0, stream>>>(part0, part1, stats, out);
}

// Round 10
// 121.062 us; speedup vs baseline: 1.1527x; 1.0783x over previous
//
#include <hip/hip_runtime.h>

// Problem constants (B=2, S=2048, H=8, E=64).
// Harness passes f16 tensors upcast to FLOAT32 (in and out). Internally f16
// compute (lossless re-narrowing of f16-origin data), fp32 MFMA accumulation.
#define S_LEN 2048
#define NH    8
#define EMB   64
#define BM    64    // q rows per block-column (16 per wave)
#define BN    64    // kv tile length (best measured: R3/R6/R8 config)
#define NKT   (S_LEN / BN)          // 32 kv tiles
#define NSPLIT 2    // KV splits (intra-block groups on the fused path)
#define M_INIT  (-1.0e4f)
#define EXP_CLAMP (-80.0f)
#define DEFER_THR 8.0f   // T13: skip rescale while max growth <= 8 (P <= e^8, f16-safe)

typedef _Float16 half8   __attribute__((ext_vector_type(8)));
typedef _Float16 half4   __attribute__((ext_vector_type(4)));
typedef float    float4_t __attribute__((ext_vector_type(4)));
typedef float    float8_t __attribute__((ext_vector_type(8)));

__device__ inline half8 cvt8(const float* p) {
    float8_t f = *reinterpret_cast<const float8_t*>(p);
    half8 h;
    #pragma unroll
    for (int j = 0; j < 8; ++j) h[j] = (_Float16)f[j];
    return h;
}

// async global->LDS, 16B per lane; LDS dest = uniform base + lane*16
__device__ inline void gload_lds16(const _Float16* g, _Float16* l) {
    __builtin_amdgcn_global_load_lds(
        (const __attribute__((address_space(1))) void*)g,
        (__attribute__((address_space(3))) void*)l, 16, 0, 0);
}

// ---------------------------------------------------------------------------
// Projection worker: one segment per 256 blocks.
//   mode 0: Q -> Qf16[bh][s][e], f16, pre-scaled by 0.125
//   mode 1: K -> KT8[bh][f/8][s][f%8]
//   mode 2: V -> VT8[bh][s/8][f][s%8]
// ---------------------------------------------------------------------------
__device__ inline void proj_body(
    int mode, int bid, const float* __restrict__ X,
    const float* __restrict__ W, const float* __restrict__ bias,
    _Float16* __restrict__ Dst)
{
    const int tid  = threadIdx.x;
    const int lane = tid & 63;
    const int wave = tid >> 6;
    const int l15  = lane & 15;
    const int quad = lane >> 4;
    const int gwave = bid * 4 + wave;

    half8 wf[4][2];
    #pragma unroll
    for (int ft = 0; ft < 4; ++ft)
        #pragma unroll
        for (int ks = 0; ks < 2; ++ks)
            wf[ft][ks] = cvt8(W + (ft * 16 + l15) * 64 + ks * 32 + quad * 8);
    float bv[4];
    #pragma unroll
    for (int ft = 0; ft < 4; ++ft) bv[ft] = bias[ft * 16 + l15];

    #pragma unroll
    for (int rt2 = 0; rt2 < 2; ++rt2) {
        const int rt = gwave * 2 + rt2;
        const int arow = rt * 16 + l15;
        half8 xf[2];
        #pragma unroll
        for (int ks = 0; ks < 2; ++ks)
            xf[ks] = cvt8(X + (long)arow * 64 + ks * 32 + quad * 8);
        float4_t acc[4];
        #pragma unroll
        for (int ft = 0; ft < 4; ++ft) {
            acc[ft] = (float4_t){0.f, 0.f, 0.f, 0.f};
            #pragma unroll
            for (int ks = 0; ks < 2; ++ks)
                acc[ft] = __builtin_amdgcn_mfma_f32_16x16x32_f16(
                    xf[ks], wf[ft][ks], acc[ft], 0, 0, 0);
        }
        #pragma unroll
        for (int r = 0; r < 4; ++r) {
            const int row = rt * 16 + quad * 4 + r;     // (b*S+s)*H+h
            const int b = row >> 14;
            const int s = (row >> 3) & 2047;
            const int h = row & 7;
            const int bh = b * NH + h;
            #pragma unroll
            for (int ft = 0; ft < 4; ++ft) {
                const _Float16 v = (_Float16)(acc[ft][r] + bv[ft]);
                const int f = ft * 16 + l15;
                if (mode == 0)
                    Dst[((long)bh * S_LEN + s) * EMB + f] = v * (_Float16)0.125f;
                else if (mode == 1)
                    Dst[(((long)bh * 8 + (f >> 3)) * S_LEN + s) * 8 + (f & 7)] = v;
                else
                    Dst[(((long)bh * 256 + (s >> 3)) * 64 + f) * 8 + (s & 7)] = v;
            }
        }
    }
}

// Fused projection launch (768 blocks): seg 0=Q, 1=K, 2=V. Destinations are
// caller-chosen (d_ws on the fused path -> no input aliasing at all).
__global__ __launch_bounds__(256) void proj_qkv(
    const float* __restrict__ q_in, const float* __restrict__ k_in,
    const float* __restrict__ v_in,
    const float* __restrict__ Wq, const float* __restrict__ bq,
    const float* __restrict__ Wk, const float* __restrict__ bk,
    const float* __restrict__ Wv, const float* __restrict__ bv_,
    _Float16* __restrict__ Qf16, _Float16* __restrict__ KT8,
    _Float16* __restrict__ VT8)
{
    const int seg = blockIdx.x >> 8;
    const int bid = blockIdx.x & 255;
    if (seg == 0)      proj_body(0, bid, q_in, Wq, bq, Qf16);
    else if (seg == 1) proj_body(1, bid, k_in, Wk, bk, KT8);
    else               proj_body(2, bid, v_in, Wv, bv_, VT8);
}

// Fallback helpers (R9 plan, used when ws_size < 12 MiB).
__global__ __launch_bounds__(256) void proj_qk(
    const float* __restrict__ q_in, const float* __restrict__ k_in,
    const float* __restrict__ Wq, const float* __restrict__ bq,
    const float* __restrict__ Wk, const float* __restrict__ bk,
    _Float16* __restrict__ Qf16, _Float16* __restrict__ KT8)
{
    const int seg = blockIdx.x >> 8;
    const int bid = blockIdx.x & 255;
    if (seg == 0) proj_body(0, bid, q_in, Wq, bq, Qf16);
    else          proj_body(1, bid, k_in, Wk, bk, KT8);
}

__global__ __launch_bounds__(256) void proj_v(
    const float* __restrict__ v_in,
    const float* __restrict__ Wv, const float* __restrict__ bv_,
    _Float16* __restrict__ VT8)
{
    proj_body(2, blockIdx.x, v_in, Wv, bv_, VT8);
}

// ---------------------------------------------------------------------------
// FUSED attention (primary path): 512-thread blocks, 2 wave-groups of 4.
// Group g runs R8's verified per-tile schedule on KV tiles [16g, 16g+16) with
// its OWN K/V double-buffer; per-CU schedule is identical to R8/R9 (2 blocks
// x 8 waves = 16 waves/CU, same 16-wave barrier-group count per CU... each
// barrier now spans 8 waves but the per-tile work per wave is unchanged).
// After the loop, group 1 publishes unnormalized (O, m, l) via the now-dead
// group-1 K-buffer region; group 0 merges (split-softmax identity, stale-m
// invariant) and writes final f32 to d_out. Deletes the combine kernel, the
// stats buffer, and 16 MiB of partials traffic.
// LDS: dynamic 81920 B = [g][K/V][buf] 4x16KB + P 8x2KB. 2 blocks/CU.
// ---------------------------------------------------------------------------
__global__ __launch_bounds__(512, 4) void attn_fused(
    const _Float16* __restrict__ KT, const _Float16* __restrict__ VT,
    const _Float16* __restrict__ Qf16, float* __restrict__ out)
{
    extern __shared__ __align__(16) char smem[];
    // layout (bytes):
    //   [0,      32768): group 0 K dbuf (2x8KB) then V dbuf (2x8KB)
    //   [32768,  65536): group 1 K dbuf + V dbuf
    //   [65536,  81920): per-wave P, wave w at 65536 + w*2048
    // merge region (after loop, group-1 K area): o1 16KB @32768 (+w4*4096),
    //   m1/l1 @49152 (+w4*128): 16 f32 m then 16 f32 l.   (g1 V area start)
    _Float16* KV = (_Float16*)smem;

    const int tid  = threadIdx.x;
    const int lane = tid & 63;
    const int wave = tid >> 6;          // 0..7
    const int g    = wave >> 2;         // KV-split group
    const int w4   = wave & 3;          // wave within group
    const int l15  = lane & 15;
    const int quad = lane >> 4;
    const int tid_g = tid & 255;        // thread id within group

    _Float16* Kb0 = KV + (g * 4 + 0) * 4096;     // buf 0
    _Float16* Kb1 = KV + (g * 4 + 1) * 4096;     // buf 1
    _Float16* Vb0 = KV + (g * 4 + 2) * 4096;
    _Float16* Vb1 = KV + (g * 4 + 3) * 4096;
    _Float16* Pw  = (_Float16*)(smem + 65536) + wave * 1024;
    float*    mrgO  = (float*)(smem + 32768);    // + w4*1024 f32
    float*    mrgML = (float*)(smem + 49152);    // + w4*32 f32

    // XCD-aware decomposition: 512 = 8 XCD * (2 heads * 32 qt)
    const int bx  = blockIdx.x;
    const int xcd = bx & 7;
    const int j   = bx >> 3;            // 0..63
    const int hh  = j >> 5;
    const int qt  = j & 31;
    const int bh  = xcd * 2 + hh;

    const int qrow0 = qt * BM + w4 * 16;          // same rows for both groups
    const _Float16* kg  = KT + (long)bh * 8 * S_LEN * 8;
    const _Float16* vgh = VT + (long)bh * 256 * 512;

    // per-thread staging bases (within group)
    const _Float16* k0 = kg + ((long)(tid_g >> 6) * S_LEN + (tid_g & 63)) * 8;
    const _Float16* k1 = kg + ((long)((tid_g >> 6) + 4) * S_LEN + (tid_g & 63)) * 8;
    const _Float16* v0 = vgh + tid_g * 8;
    const _Float16* v1 = vgh + (256 + tid_g) * 8;

    const int kb = g * (NKT / NSPLIT);            // 16 tiles per group

    // ---- prologue: stage tile kb into buffer 0; load Q frags meanwhile ----
    {
        const long t8  = (long)(kb * BN) * 8;
        const long t64 = (long)(kb * BN) * 64;
        gload_lds16(k0 + t8,  Kb0 + tid_g * 8);
        gload_lds16(k1 + t8,  Kb0 + (256 + tid_g) * 8);
        gload_lds16(v0 + t64, Vb0 + tid_g * 8);
        gload_lds16(v1 + t64, Vb0 + (256 + tid_g) * 8);
    }

    half8 qf[2];   // B-frag: Q[n = q-row l15][e = ks*32+quad*8+j] (f16 direct)
    {
        const _Float16* qrow = Qf16 + ((long)bh * S_LEN + qrow0 + l15) * EMB;
        qf[0] = *reinterpret_cast<const half8*>(qrow + quad * 8);
        qf[1] = *reinterpret_cast<const half8*>(qrow + 32 + quad * 8);
    }

    half8 vones;
    #pragma unroll
    for (int jj = 0; jj < 8; ++jj) vones[jj] = (_Float16)1.0f;

    float4_t o[4];
    #pragma unroll
    for (int et = 0; et < 4; ++et) o[et] = (float4_t){0.f, 0.f, 0.f, 0.f};
    float4_t lacc = (float4_t){0.f, 0.f, 0.f, 0.f};  // P row-sums, rows quad*4+r
    float m_run = M_INIT;

    const int pswz = (l15 & 7) << 3;      // P column XOR-swizzle
    __syncthreads();                      // drains prologue vmcnt

    for (int it = 0; it < NKT / NSPLIT; ++it) {
        const int cur = it & 1;
        const bool more = (it + 1 < NKT / NSPLIT);

        // ---- issue next tile's staging into the other buffer ----
        if (more) {
            const long t8  = (long)((kb + it + 1) * BN) * 8;
            const long t64 = (long)((kb + it + 1) * BN) * 64;
            _Float16* kd = cur ? Kb0 : Kb1;
            _Float16* vd = cur ? Vb0 : Vb1;
            gload_lds16(k0 + t8,  kd + tid_g * 8);
            gload_lds16(k1 + t8,  kd + (256 + tid_g) * 8);
            gload_lds16(v0 + t64, vd + tid_g * 8);
            gload_lds16(v1 + t64, vd + (256 + tid_g) * 8);
        }

        const _Float16* Kc = cur ? Kb1 : Kb0;
        const _Float16* Vc = cur ? Vb1 : Vb0;

        // ---- S^T = K Q^T : 4 n-tiles of 16 t-rows ----
        float4_t sacc[4];
        #pragma unroll
        for (int nt = 0; nt < 4; ++nt) sacc[nt] = (float4_t){0.f, 0.f, 0.f, 0.f};
        __builtin_amdgcn_s_setprio(1);
        #pragma unroll
        for (int nt = 0; nt < 4; ++nt)
            #pragma unroll
            for (int ks = 0; ks < 2; ++ks) {
                half8 kf = *reinterpret_cast<const half8*>(
                    Kc + (ks * 4 + quad) * 512 + (nt * 16 + l15) * 8);
                sacc[nt] = __builtin_amdgcn_mfma_f32_16x16x32_f16(
                    kf, qf[ks], sacc[nt], 0, 0, 0);
            }
        __builtin_amdgcn_s_setprio(0);

        // ---- local max (fused max3 tree) ----
        float mx = fmaxf(fmaxf(sacc[0][0], sacc[0][1]),
                         fmaxf(sacc[0][2], sacc[0][3]));
        mx = fmaxf(fmaxf(mx, sacc[1][0]), sacc[1][1]);
        mx = fmaxf(fmaxf(mx, sacc[1][2]), sacc[1][3]);
        mx = fmaxf(fmaxf(mx, sacc[2][0]), sacc[2][1]);
        mx = fmaxf(fmaxf(mx, sacc[2][2]), sacc[2][3]);
        mx = fmaxf(fmaxf(mx, sacc[3][0]), sacc[3][1]);
        mx = fmaxf(fmaxf(mx, sacc[3][2]), sacc[3][3]);

        // T13 defer (per-wave vote)
        if (!__all(mx - m_run <= DEFER_THR)) {
            float mr = fmaxf(mx, __shfl_xor(mx, 16));
            mr = fmaxf(mr, __shfl_xor(mr, 32));
            const float mn = fmaxf(m_run, mr);
            const float alpha = __expf(fmaxf(m_run - mn, EXP_CLAMP));
            m_run = mn;
            #pragma unroll
            for (int r = 0; r < 4; ++r) {
                const float ar = __shfl(alpha, quad * 4 + r);
                lacc[r] *= ar;
                #pragma unroll
                for (int et = 0; et < 4; ++et) o[et][r] *= ar;
            }
        }

        // ---- exp + ALL P stores -> ONE LDS wait -> both A-frags ----
        #pragma unroll
        for (int nt = 0; nt < 4; ++nt) {
            half4 ph;
            #pragma unroll
            for (int r = 0; r < 4; ++r)
                ph[r] = (_Float16)__expf(sacc[nt][r] - m_run);
            *reinterpret_cast<half4*>(
                &Pw[l15 * 64 + ((nt * 16 + quad * 4) ^ pswz)]) = ph;
        }
        half8 pf0 = *reinterpret_cast<const half8*>(
            &Pw[l15 * 64 + ((quad * 8) ^ pswz)]);
        half8 pf1 = *reinterpret_cast<const half8*>(
            &Pw[l15 * 64 + ((32 + quad * 8) ^ pswz)]);

        // ---- PV + l: 20 MFMAs in one burst ----
        __builtin_amdgcn_s_setprio(1);
        #pragma unroll
        for (int et = 0; et < 4; ++et) {
            half8 vf = *reinterpret_cast<const half8*>(
                Vc + quad * 512 + (et * 16 + l15) * 8);
            o[et] = __builtin_amdgcn_mfma_f32_16x16x32_f16(pf0, vf, o[et], 0, 0, 0);
        }
        lacc = __builtin_amdgcn_mfma_f32_16x16x32_f16(pf0, vones, lacc, 0, 0, 0);
        #pragma unroll
        for (int et = 0; et < 4; ++et) {
            half8 vf = *reinterpret_cast<const half8*>(
                Vc + (4 + quad) * 512 + (et * 16 + l15) * 8);
            o[et] = __builtin_amdgcn_mfma_f32_16x16x32_f16(pf1, vf, o[et], 0, 0, 0);
        }
        lacc = __builtin_amdgcn_mfma_f32_16x16x32_f16(pf1, vones, lacc, 0, 0, 0);
        __builtin_amdgcn_s_setprio(0);

        if (more) __syncthreads();
    }

    // ---- intra-block combine: group 1 publishes, group 0 merges+writes ----
    __syncthreads();                      // all waves done with loop buffers
    if (g == 1) {
        float* mo = mrgO + w4 * 1024;     // [row][col] f32, 16x64
        #pragma unroll
        for (int r = 0; r < 4; ++r)
            #pragma unroll
            for (int et = 0; et < 4; ++et)
                mo[(quad * 4 + r) * 64 + et * 16 + l15] = o[et][r];
        if (lane < 16) mrgML[w4 * 32 + lane] = m_run;           // m1[row]
        if (l15 == 0) {                                          // l1[row]
            #pragma unroll
            for (int r = 0; r < 4; ++r)
                mrgML[w4 * 32 + 16 + quad * 4 + r] = lacc[r];
        }
    }
    __syncthreads();
    if (g == 0) {
        const float* mo = mrgO + w4 * 1024;
        #pragma unroll
        for (int r = 0; r < 4; ++r) {
            const int row = quad * 4 + r;
            const float m0r = __shfl(m_run, row);               // own group m
            const float m1r = mrgML[w4 * 32 + row];
            const float l1r = mrgML[w4 * 32 + 16 + row];
            const float M = fmaxf(m0r, m1r);
            const float e0 = __expf(fmaxf(m0r - M, EXP_CLAMP));
            const float e1 = __expf(fmaxf(m1r - M, EXP_CLAMP));
            const float inv = 1.f / (lacc[r] * e0 + l1r * e1);
            const float w0 = e0 * inv, w1 = e1 * inv;
            const long orow = ((long)bh * S_LEN + qrow0 + row) * EMB;
            #pragma unroll
            for (int et = 0; et < 4; ++et) {
                const float val = o[et][r] * w0 +
                                  mo[row * 64 + et * 16 + l15] * w1;
                out[orow + et * 16 + l15] = (float)(_Float16)val;
            }
        }
    }
}

// ---------------------------------------------------------------------------
// Fallback attention (R9 plan): split across blocks + combine kernel.
// ---------------------------------------------------------------------------
__global__ __launch_bounds__(256, 4) void attn_part(
    const _Float16* __restrict__ KT, const _Float16* __restrict__ VT,
    const _Float16* __restrict__ Qf16,
    _Float16* __restrict__ p0, _Float16* __restrict__ p1,
    float* __restrict__ stats)
{
    __shared__ __align__(16) _Float16 Kb[2][8 * 64 * 8];
    __shared__ __align__(16) _Float16 Vb[2][8 * 64 * 8];
    __shared__ __align__(16) _Float16 Pl[4][16 * 64];

    const int tid  = threadIdx.x;
    const int lane = tid & 63;
    const int wave = tid >> 6;
    const int l15  = lane & 15;
    const int quad = lane >> 4;

    const int bx     = blockIdx.x;
    const int xcd    = bx & 7;
    const int j      = bx >> 3;
    const int hh     = j >> 6;
    const int within = j & 63;
    const int bh     = xcd * 2 + hh;
    const int qt     = within >> 1;
    const int sp     = within & 1;

    const int qrow0 = qt * BM + wave * 16;
    const _Float16* kg  = KT + (long)bh * 8 * S_LEN * 8;
    const _Float16* vgh = VT + (long)bh * 256 * 512;

    const _Float16* k0 = kg + ((long)(tid >> 6) * S_LEN + (tid & 63)) * 8;
    const _Float16* k1 = kg + ((long)((tid >> 6) + 4) * S_LEN + (tid & 63)) * 8;
    const _Float16* v0 = vgh + tid * 8;
    const _Float16* v1 = vgh + (256 + tid) * 8;

    const int kb = sp * (NKT / NSPLIT), ke = kb + (NKT / NSPLIT);

    {
        const long t8  = (long)(kb * BN) * 8;
        const long t64 = (long)(kb * BN) * 64;
        gload_lds16(k0 + t8,  &Kb[0][tid * 8]);
        gload_lds16(k1 + t8,  &Kb[0][(256 + tid) * 8]);
        gload_lds16(v0 + t64, &Vb[0][tid * 8]);
        gload_lds16(v1 + t64, &Vb[0][(256 + tid) * 8]);
    }

    half8 qf[2];
    {
        const _Float16* qrow = Qf16 + ((long)bh * S_LEN + qrow0 + l15) * EMB;
        qf[0] = *reinterpret_cast<const half8*>(qrow + quad * 8);
        qf[1] = *reinterpret_cast<const half8*>(qrow + 32 + quad * 8);
    }

    half8 vones;
    #pragma unroll
    for (int jj = 0; jj < 8; ++jj) vones[jj] = (_Float16)1.0f;

    float4_t o[4];
    #pragma unroll
    for (int et = 0; et < 4; ++et) o[et] = (float4_t){0.f, 0.f, 0.f, 0.f};
    float4_t lacc = (float4_t){0.f, 0.f, 0.f, 0.f};
    float m_run = M_INIT;

    const int pswz = (l15 & 7) << 3;
    _Float16* Pw = Pl[wave];

    __syncthreads();

    for (int kt = kb; kt < ke; ++kt) {
        const int cur = (kt - kb) & 1;
        const bool more = (kt + 1 < ke);

        if (more) {
            const long t8  = (long)((kt + 1) * BN) * 8;
            const long t64 = (long)((kt + 1) * BN) * 64;
            _Float16* kd = Kb[cur ^ 1];
            _Float16* vd = Vb[cur ^ 1];
            gload_lds16(k0 + t8,  kd + tid * 8);
            gload_lds16(k1 + t8,  kd + (256 + tid) * 8);
            gload_lds16(v0 + t64, vd + tid * 8);
            gload_lds16(v1 + t64, vd + (256 + tid) * 8);
        }

        const _Float16* Kc = Kb[cur];
        const _Float16* Vc = Vb[cur];

        float4_t sacc[4];
        #pragma unroll
        for (int nt = 0; nt < 4; ++nt) sacc[nt] = (float4_t){0.f, 0.f, 0.f, 0.f};
        __builtin_amdgcn_s_setprio(1);
        #pragma unroll
        for (int nt = 0; nt < 4; ++nt)
            #pragma unroll
            for (int ks = 0; ks < 2; ++ks) {
                half8 kf = *reinterpret_cast<const half8*>(
                    Kc + (ks * 4 + quad) * 512 + (nt * 16 + l15) * 8);
                sacc[nt] = __builtin_amdgcn_mfma_f32_16x16x32_f16(
                    kf, qf[ks], sacc[nt], 0, 0, 0);
            }
        __builtin_amdgcn_s_setprio(0);

        float mx = fmaxf(fmaxf(sacc[0][0], sacc[0][1]),
                         fmaxf(sacc[0][2], sacc[0][3]));
        mx = fmaxf(fmaxf(mx, sacc[1][0]), sacc[1][1]);
        mx = fmaxf(fmaxf(mx, sacc[1][2]), sacc[1][3]);
        mx = fmaxf(fmaxf(mx, sacc[2][0]), sacc[2][1]);
        mx = fmaxf(fmaxf(mx, sacc[2][2]), sacc[2][3]);
        mx = fmaxf(fmaxf(mx, sacc[3][0]), sacc[3][1]);
        mx = fmaxf(fmaxf(mx, sacc[3][2]), sacc[3][3]);

        if (!__all(mx - m_run <= DEFER_THR)) {
            float mr = fmaxf(mx, __shfl_xor(mx, 16));
            mr = fmaxf(mr, __shfl_xor(mr, 32));
            const float mn = fmaxf(m_run, mr);
            const float alpha = __expf(fmaxf(m_run - mn, EXP_CLAMP));
            m_run = mn;
            #pragma unroll
            for (int r = 0; r < 4; ++r) {
                const float ar = __shfl(alpha, quad * 4 + r);
                lacc[r] *= ar;
                #pragma unroll
                for (int et = 0; et < 4; ++et) o[et][r] *= ar;
            }
        }

        #pragma unroll
        for (int nt = 0; nt < 4; ++nt) {
            half4 ph;
            #pragma unroll
            for (int r = 0; r < 4; ++r)
                ph[r] = (_Float16)__expf(sacc[nt][r] - m_run);
            *reinterpret_cast<half4*>(
                &Pw[l15 * 64 + ((nt * 16 + quad * 4) ^ pswz)]) = ph;
        }
        half8 pf0 = *reinterpret_cast<const half8*>(
            &Pw[l15 * 64 + ((quad * 8) ^ pswz)]);
        half8 pf1 = *reinterpret_cast<const half8*>(
            &Pw[l15 * 64 + ((32 + quad * 8) ^ pswz)]);

        __builtin_amdgcn_s_setprio(1);
        #pragma unroll
        for (int et = 0; et < 4; ++et) {
            half8 vf = *reinterpret_cast<const half8*>(
                Vc + quad * 512 + (et * 16 + l15) * 8);
            o[et] = __builtin_amdgcn_mfma_f32_16x16x32_f16(pf0, vf, o[et], 0, 0, 0);
        }
        lacc = __builtin_amdgcn_mfma_f32_16x16x32_f16(pf0, vones, lacc, 0, 0, 0);
        #pragma unroll
        for (int et = 0; et < 4; ++et) {
            half8 vf = *reinterpret_cast<const half8*>(
                Vc + (4 + quad) * 512 + (et * 16 + l15) * 8);
            o[et] = __builtin_amdgcn_mfma_f32_16x16x32_f16(pf1, vf, o[et], 0, 0, 0);
        }
        lacc = __builtin_amdgcn_mfma_f32_16x16x32_f16(pf1, vones, lacc, 0, 0, 0);
        __builtin_amdgcn_s_setprio(0);

        if (more) __syncthreads();
    }

    _Float16* pp = (sp == 0) ? p0 : p1;
    #pragma unroll
    for (int r = 0; r < 4; ++r) {
        const float inv = 1.f / lacc[r];
        const int row = qrow0 + quad * 4 + r;
        const int R = bh * S_LEN + row;
        #pragma unroll
        for (int et = 0; et < 4; ++et)
            pp[(long)R * EMB + et * 16 + l15] = (_Float16)(o[et][r] * inv);
    }
    {
        const int srcl = (lane >> 2) * 16;
        const float s0 = __shfl(lacc[0], srcl);
        const float s1 = __shfl(lacc[1], srcl);
        const float s2 = __shfl(lacc[2], srcl);
        const float s3 = __shfl(lacc[3], srcl);
        const int rr = lane & 3;
        const float lsel = (rr == 0) ? s0 : (rr == 1) ? s1 : (rr == 2) ? s2 : s3;
        if (lane < 16) {
            const int R = bh * S_LEN + qrow0 + lane;
            stats[sp * 32768 + R] = m_run;
            stats[(NSPLIT + sp) * 32768 + R] = lsel;
        }
    }
}

__global__ __launch_bounds__(256) void attn_combine(
    const _Float16* __restrict__ p0, const _Float16* __restrict__ p1,
    const float* __restrict__ stats, float* __restrict__ out)
{
    const int gid = blockIdx.x * 256 + threadIdx.x;
    const int R  = gid >> 2;
    const int c0 = (gid & 3) * 16;
    const float m0 = stats[R], m1 = stats[32768 + R];
    const float l0 = stats[2 * 32768 + R], l1 = stats[3 * 32768 + R];
    const float M = fmaxf(m0, m1);
    float w0 = l0 * __expf(fmaxf(m0 - M, EXP_CLAMP));
    float w1 = l1 * __expf(fmaxf(m1 - M, EXP_CLAMP));
    const float rinv = 1.f / (w0 + w1);
    w0 *= rinv; w1 *= rinv;
    const long i0 = (long)R * EMB + c0;
    #pragma unroll
    for (int h = 0; h < 2; ++h) {
        half8 a = *reinterpret_cast<const half8*>(p0 + i0 + h * 8);
        half8 b = *reinterpret_cast<const half8*>(p1 + i0 + h * 8);
        #pragma unroll
        for (int j = 0; j < 8; ++j)
            out[i0 + h * 8 + j] = (float)(_Float16)(
                w0 * (float)a[j] + w1 * (float)b[j]);
    }
}

// ---------------------------------------------------------------------------
// Primary path (ws >= 12 MiB): 2 launches, everything staged in d_ws.
//   L1 proj_qkv: reads d_in[0..2] + weights; writes d_ws[0,12MiB) only.
//   L2 attn_fused: reads d_ws; writes d_out f32 directly. No combine.
// Fallback (R9 plan) otherwise.
// ---------------------------------------------------------------------------
extern "C" void kernel_launch(void* const* d_in, const int* in_sizes, int n_in,
                              void* d_out, int out_size, void* d_ws, size_t ws_size,
                              hipStream_t stream) {
    const float* q_in = (const float*)d_in[0];
    const float* k_in = (const float*)d_in[1];
    const float* v_in = (const float*)d_in[2];
    const float* Wq   = (const float*)d_in[3];
    const float* bq   = (const float*)d_in[4];
    const float* Wk   = (const float*)d_in[5];
    const float* bk   = (const float*)d_in[6];
    const float* Wv   = (const float*)d_in[7];
    const float* bv   = (const float*)d_in[8];
    float* out = (float*)d_out;

    if (ws_size >= (size_t)(12u << 20)) {
        _Float16* Qf16 = (_Float16*)d_ws;                         // 4 MiB
        _Float16* KT8  = (_Float16*)((char*)d_ws + (4u << 20));   // 4 MiB
        _Float16* VT8  = (_Float16*)((char*)d_ws + (8u << 20));   // 4 MiB
        proj_qkv<<<768, 256, 0, stream>>>(q_in, k_in, v_in, Wq, bq, Wk, bk,
                                          Wv, bv, Qf16, KT8, VT8);
        attn_fused<<<512, 512, 81920, stream>>>(KT8, VT8, Qf16, out);
    } else {
        // R9 fallback: Qf16/KT8 in d_out, VT8 in d_in[1] (or d_ws if >=4MiB),
        // partials in d_in[2], stats in d_in[0], combine writes d_out.
        _Float16* Qf16  = (_Float16*)d_out;
        _Float16* KT8   = (_Float16*)((char*)d_out + (4u << 20));
        _Float16* part0 = (_Float16*)d_in[2];
        _Float16* part1 = part0 + (long)2 * 1024 * 1024;
        float*    stats = (float*)d_in[0];
        _Float16* VT8;
        if (ws_size >= (size_t)(4u << 20)) {
            VT8 = (_Float16*)d_ws;
            proj_qkv<<<768, 256, 0, stream>>>(q_in, k_in, v_in, Wq, bq, Wk, bk,
                                              Wv, bv, Qf16, KT8, VT8);
        } else {
            VT8 = (_Float16*)d_in[1];
            proj_qk<<<512, 256, 0, stream>>>(q_in, k_in, Wq, bq, Wk, bk,
                                             Qf16, KT8);
            proj_v<<<256, 256, 0, stream>>>(v_in, Wv, bv, VT8);
        }
        attn_part<<<16 * 32 * NSPLIT, 256, 0, stream>>>(KT8, VT8, Qf16,
                                                        part0, part1, stats);
        attn_combine<<<512, 256, 0, stream>>>(part0, part1, stats, out);
    }
}